// Round 10
// baseline (5660.767 us; speedup 1.0000x reference)
//
#include <hip/hip_runtime.h>

#define NP   16384
#define KNN  32
#define HDIM 128
#define ODIM 64

// ---------------- squared norms ----------------
template<int D>
__global__ __launch_bounds__(256)
void sq_kernel(const float* __restrict__ X, float* __restrict__ sq) {
    const int lane = threadIdx.x & 63;
    const int row  = blockIdx.x * 4 + (threadIdx.x >> 6);
    float s = 0.f;
    #pragma unroll
    for (int d = lane; d < D; d += 64) {
        const float v = X[(size_t)row * D + d];
        s = fmaf(v, v, s);
    }
    #pragma unroll
    for (int off = 32; off; off >>= 1) s += __shfl_down(s, off);
    if (lane == 0) sq[row] = s;
}

// ---------------- top-32 neighbors (streaming, sorted register top-k) -------
// score_j = dot(x_i,x_j) - 0.5*sq_j (argmax score == argmin d2 per row).
// R8 geometry: TI=32 rows/block, JC=128 cols/tile, 8 waves, R=4 rows/wave,
// grid=512 (2 blocks/CU). This round: xi operands via VMEM broadcast loads
// (wave-uniform addr, L1-resident, depth-1 prefetch) instead of per-tile
// s_load chains; D=64 uses LDS double-buffer -> 1 barrier/tile.
// Top-32 SORTED (value desc, index asc on ties) in lanes 0..31.
template<int D>
__global__ __launch_bounds__(512)
void topk_kernel(const float* __restrict__ X, const float* __restrict__ sq,
                 int* __restrict__ topIdx) {
    constexpr int TI = 32, JC = 128;
    constexpr int R  = TI / 8;                 // rows per wave = 4
    constexpr int NT = NP / JC;                // 128 tiles
    constexpr int NSTG = JC * D / 4 / 512;     // float4/thread per j-tile
    constexpr bool DBUF = (D == 64);
    constexpr int BUFSZ = (D / 2) * JC;        // float2 elements per buffer
    __shared__ float2 xjP[(DBUF ? 2 : 1) * BUFSZ];

    const int t = threadIdx.x;
    const int lane = t & 63;
    const int wave = t >> 6;                   // NOT readfirstlane: keep divergent
    const int rowBase = blockIdx.x * TI;       //  -> xi loads become VMEM broadcast
    const float* __restrict__ xr = X + (size_t)(rowBase + wave * R) * D;
    const float INF = __builtin_inff();

    // sorted top-32 per row: lane l<32 holds rank-l entry (desc value)
    float tv[R]; int tidx[R]; float minv[R];
    #pragma unroll
    for (int r = 0; r < R; ++r) { tv[r] = -INF; tidx[r] = 0x7fffffff; minv[r] = -INF; }

    float4 stg[NSTG];
    auto loadTile = [&](int jb) {
        #pragma unroll
        for (int s = 0; s < NSTG; ++s) {
            const int e = s * 512 + t;
            const int j = e & (JC - 1), dg = e >> 7;
            stg[s] = *reinterpret_cast<const float4*>(X + (size_t)(jb + j) * D + 4 * dg);
        }
    };
    auto writeTile = [&](int buf) {
        float2* const dst = xjP + buf * BUFSZ;
        #pragma unroll
        for (int s = 0; s < NSTG; ++s) {
            const int e = s * 512 + t;
            const int j = e & (JC - 1), dg = e >> 7;
            dst[(2 * dg + 0) * JC + j] = make_float2(stg[s].x, stg[s].y);
            dst[(2 * dg + 1) * JC + j] = make_float2(stg[s].z, stg[s].w);
        }
    };

    // prologue
    loadTile(0);
    writeTile(0);
    loadTile(JC);                              // tile 1 into regs
    if (!DBUF) { __syncthreads(); }            // dbuf path syncs below
    if (DBUF) __syncthreads();

    for (int it = 0; it < NT; ++it) {
        const int jb = it * JC;
        const int bufR = DBUF ? (it & 1) : 0;
        const float sub0 = 0.5f * sq[jb + lane];        // issued early, used in scan
        const float sub1 = 0.5f * sq[jb + 64 + lane];

        if (DBUF) {
            if (it + 1 < NT) writeTile(bufR ^ 1);       // other buffer: no hazard
        }

        // GEMM: 4 rows (VMEM-broadcast xi, depth-1 prefetch) x 2 cols per lane
        const float2* const xb = xjP + bufR * BUFSZ;
        float acc0[R], acc1[R];
        #pragma unroll
        for (int r = 0; r < R; ++r) { acc0[r] = 0.f; acc1[r] = 0.f; }

        float4 aC[R], aN[R];
        #pragma unroll
        for (int r = 0; r < R; ++r)
            aC[r] = *reinterpret_cast<const float4*>(xr + (size_t)r * D);

        #pragma unroll 4
        for (int pg = 0; pg < D / 4; ++pg) {            // 4 d's per iter
            if (pg + 1 < D / 4) {
                #pragma unroll
                for (int r = 0; r < R; ++r)
                    aN[r] = *reinterpret_cast<const float4*>(
                        xr + (size_t)r * D + 4 * (pg + 1));
            }
            const float2 b00 = xb[(2 * pg + 0) * JC + lane];
            const float2 b01 = xb[(2 * pg + 0) * JC + 64 + lane];
            const float2 b10 = xb[(2 * pg + 1) * JC + lane];
            const float2 b11 = xb[(2 * pg + 1) * JC + 64 + lane];
            #pragma unroll
            for (int r = 0; r < R; ++r) {               // d-ascending (numerics)
                acc0[r] = fmaf(aC[r].x, b00.x, acc0[r]);
                acc0[r] = fmaf(aC[r].y, b00.y, acc0[r]);
                acc0[r] = fmaf(aC[r].z, b10.x, acc0[r]);
                acc0[r] = fmaf(aC[r].w, b10.y, acc0[r]);
                acc1[r] = fmaf(aC[r].x, b01.x, acc1[r]);
                acc1[r] = fmaf(aC[r].y, b01.y, acc1[r]);
                acc1[r] = fmaf(aC[r].z, b11.x, acc1[r]);
                acc1[r] = fmaf(aC[r].w, b11.y, acc1[r]);
            }
            #pragma unroll
            for (int r = 0; r < R; ++r) aC[r] = aN[r];
        }

        if (!DBUF) {
            __syncthreads();                   // all waves done reading xjP
            if (it + 1 < NT) writeTile(0);
            __syncthreads();                   // next tile staged
        }
        if (it + 2 < NT) loadTile(jb + 2 * JC);  // prefetch into stg (after writes)

        // scan: sorted-insert top-k; stale minv + p==32 self-filter; rows interleaved
        #pragma unroll
        for (int h = 0; h < 2; ++h) {
            float sv[R];
            unsigned long long m[R];
            #pragma unroll
            for (int r = 0; r < R; ++r) {
                sv[r] = (h ? acc1[r] : acc0[r]) - (h ? sub1 : sub0);
                m[r] = __ballot(sv[r] > minv[r]);
            }
            while (m[0] | m[1] | m[2] | m[3]) {
                #pragma unroll
                for (int r = 0; r < R; ++r) {
                    if (m[r]) {
                        const int l = __builtin_ctzll(m[r]);  // ascending j => stable
                        m[r] &= m[r] - 1;
                        const float cv = __shfl(sv[r], l);
                        const int   cj = jb + h * 64 + l;
                        const float upv = __shfl_up(tv[r], 1);   // hoisted off chain
                        const int   upi = __shfl_up(tidx[r], 1);
                        const bool ge = (lane < KNN) && (tv[r] >= cv);
                        const int p = __popcll(__ballot(ge));    // ==32 -> no-op
                        if (lane == p)                   { tv[r] = cv;  tidx[r] = cj; }
                        else if (lane > p && lane < KNN) { tv[r] = upv; tidx[r] = upi; }
                    }
                }
            }
        }
        #pragma unroll
        for (int r = 0; r < R; ++r)
            minv[r] = __shfl(tv[r], KNN - 1);   // exact refresh, once per tile

        if (DBUF) __syncthreads();              // single barrier per tile
    }

    if (lane < KNN) {
        #pragma unroll
        for (int r = 0; r < R; ++r)
            topIdx[(size_t)(rowBase + wave * R + r) * KNN + lane] = tidx[r];
    }
}

// ---------------- gather + MLP + pool + out ----------------
// h_k = A@nbr_k + B@x; pooled = mean_k clip(h_k); out = [pooled, x] @ W2^T.
// Wave -> (row, k-group); neighbor rows via uniform s_load (no LDS gather).
// Lane -> hh pair {2l, 2l+1}: A/B weights as float2 LDS reads (2-way = free).
template<int D, int LAYER>
__global__ __launch_bounds__(512)
void mlp_kernel(const float* __restrict__ X, const int* __restrict__ topIdx,
                const float* __restrict__ W, const float* __restrict__ W2,
                float* __restrict__ out) {
    constexpr int RPB = 2, WPR = 4, KPT = 8;   // 8 waves = RPB rows x WPR k-groups
    constexpr int W2C  = HDIM + D;
    constexpr int SPL2 = 512 / (RPB * ODIM);   // 4
    constexpr int CL   = W2C / SPL2;
    __shared__ float AT[D * HDIM];             // [d][hh]: B^T first, then A^T
    __shared__ float xi[RPB][D];
    __shared__ float part[RPB][WPR][HDIM];

    const int t = threadIdx.x;
    const int lane = t & 63;
    const int waveU = __builtin_amdgcn_readfirstlane(t >> 6);
    const int rowBase = blockIdx.x * RPB;
    const int row = waveU / WPR;
    const int wkb = waveU % WPR;
    const int hh2 = 2 * lane;                  // lane's hh pair

    // phase 0: stage xi and B^T
    if (t < RPB * D / 4) {
        const int i = t / (D / 4), dg = t % (D / 4);
        const float4 v = *reinterpret_cast<const float4*>(
            X + (size_t)(rowBase + i) * D + 4 * dg);
        xi[i][4 * dg + 0] = v.x; xi[i][4 * dg + 1] = v.y;
        xi[i][4 * dg + 2] = v.z; xi[i][4 * dg + 3] = v.w;
    }
    for (int e = t; e < HDIM * D / 4; e += 512) {
        const int hh = e % HDIM, dg = e / HDIM;
        const float4 v = *reinterpret_cast<const float4*>(
            W + (size_t)hh * (2 * D) + D + 4 * dg);          // B = W[:, D:2D]
        AT[(4 * dg + 0) * HDIM + hh] = v.x; AT[(4 * dg + 1) * HDIM + hh] = v.y;
        AT[(4 * dg + 2) * HDIM + hh] = v.z; AT[(4 * dg + 3) * HDIM + hh] = v.w;
    }
    __syncthreads();

    // phase 1: hself (lane's 2 hh) in registers
    float hs0 = 0.f, hs1 = 0.f;
    #pragma unroll 8
    for (int d = 0; d < D; ++d) {
        const float a = xi[row][d];            // broadcast LDS read
        const float2 b = *reinterpret_cast<const float2*>(&AT[d * HDIM + hh2]);
        hs0 = fmaf(b.x, a, hs0);
        hs1 = fmaf(b.y, a, hs1);
    }
    __syncthreads();                           // done reading AT-as-B^T

    // phase 1b: restage A^T
    for (int e = t; e < HDIM * D / 4; e += 512) {
        const int hh = e % HDIM, dg = e / HDIM;
        const float4 v = *reinterpret_cast<const float4*>(
            W + (size_t)hh * (2 * D) + 4 * dg);              // A = W[:, 0:D]
        AT[(4 * dg + 0) * HDIM + hh] = v.x; AT[(4 * dg + 1) * HDIM + hh] = v.y;
        AT[(4 * dg + 2) * HDIM + hh] = v.z; AT[(4 * dg + 3) * HDIM + hh] = v.w;
    }
    __syncthreads();

    // phase 2: GEMM; B-operand (neighbor rows) via uniform s_load
    const int* __restrict__ tIdx = topIdx + (size_t)(rowBase + row) * KNN + wkb * KPT;
    const float* nrow[KPT];
    #pragma unroll
    for (int r = 0; r < KPT; ++r)
        nrow[r] = X + (size_t)tIdx[r] * D;

    float acc0[KPT], acc1[KPT];
    #pragma unroll
    for (int r = 0; r < KPT; ++r) { acc0[r] = 0.f; acc1[r] = 0.f; }

    for (int dg = 0; dg < D / 4; ++dg) {
        float4 b[KPT];
        #pragma unroll
        for (int r = 0; r < KPT; ++r)          // uniform -> s_load_dwordx4
            b[r] = *reinterpret_cast<const float4*>(nrow[r] + 4 * dg);
        const float2 a0 = *reinterpret_cast<const float2*>(&AT[(4 * dg + 0) * HDIM + hh2]);
        const float2 a1 = *reinterpret_cast<const float2*>(&AT[(4 * dg + 1) * HDIM + hh2]);
        const float2 a2 = *reinterpret_cast<const float2*>(&AT[(4 * dg + 2) * HDIM + hh2]);
        const float2 a3 = *reinterpret_cast<const float2*>(&AT[(4 * dg + 3) * HDIM + hh2]);
        #pragma unroll
        for (int r = 0; r < KPT; ++r) {        // d-ascending accumulation
            acc0[r] = fmaf(a0.x, b[r].x, acc0[r]); acc1[r] = fmaf(a0.y, b[r].x, acc1[r]);
            acc0[r] = fmaf(a1.x, b[r].y, acc0[r]); acc1[r] = fmaf(a1.y, b[r].y, acc1[r]);
            acc0[r] = fmaf(a2.x, b[r].z, acc0[r]); acc1[r] = fmaf(a2.y, b[r].z, acc1[r]);
            acc0[r] = fmaf(a3.x, b[r].w, acc0[r]); acc1[r] = fmaf(a3.y, b[r].w, acc1[r]);
        }
    }

    // pooling partials (clip then sum over this wave's KPT neighbors)
    float p0 = 0.f, p1 = 0.f;
    #pragma unroll
    for (int r = 0; r < KPT; ++r) {
        p0 += fminf(1.f, fmaxf(-1.f, acc0[r] + hs0));
        p1 += fminf(1.f, fmaxf(-1.f, acc1[r] + hs1));
    }
    *reinterpret_cast<float2*>(&part[row][wkb][hh2]) =
        make_float2(p0 * (1.f / KNN), p1 * (1.f / KNN));
    __syncthreads();

    // phase 3: out = [pooled, x] @ W2^T, split over SPL2 column chunks
    {
        const int og   = t / SPL2;
        const int spl  = t % SPL2;
        const int orow = og >> 6, o = og & 63;
        const int c0   = spl * CL;
        float s = 0.f;
        for (int c = c0; c < c0 + CL; ++c) {
            float vsrc;
            if (c < HDIM) {
                vsrc = part[orow][0][c] + part[orow][1][c]
                     + part[orow][2][c] + part[orow][3][c];
            } else {
                vsrc = xi[orow][c - HDIM];
            }
            s = fmaf(vsrc, W2[(size_t)o * W2C + c], s);
        }
        #pragma unroll
        for (int off = SPL2 / 2; off; off >>= 1) s += __shfl_down(s, off);
        if (spl == 0) {
            if (LAYER == 0)
                out[(size_t)(rowBase + orow) * 128 + 64 + o] = s;  // x1 cols 64..127
            else
                out[(size_t)(rowBase + orow) * ODIM + o] = s;      // final output
        }
    }
    if (LAYER == 0 && t < RPB * 64) {
        const int orow = t >> 6, d = t & 63;
        out[(size_t)(rowBase + orow) * 128 + d] = xi[orow][d];     // x1 cols 0..63
    }
}

extern "C" void kernel_launch(void* const* d_in, const int* in_sizes, int n_in,
                              void* d_out, int out_size, void* d_ws, size_t ws_size,
                              hipStream_t stream) {
    const float* x    = (const float*)d_in[0];
    const float* w0   = (const float*)d_in[1];
    const float* w2_0 = (const float*)d_in[2];
    const float* w1   = (const float*)d_in[3];
    const float* w2_1 = (const float*)d_in[4];
    float* out = (float*)d_out;

    char* ws = (char*)d_ws;
    float* sq  = (float*)ws;                                     // NP floats
    int*   idx = (int*)(ws + (size_t)NP * 4);                    // NP*32 ints
    float* x1  = (float*)(ws + (size_t)NP * 4 + (size_t)NP * KNN * 4);  // NP*128

    // layer 0 (D = 64)
    sq_kernel<64><<<NP / 4, 256, 0, stream>>>(x, sq);
    topk_kernel<64><<<NP / 32, 512, 0, stream>>>(x, sq, idx);
    mlp_kernel<64, 0><<<NP / 2, 512, 0, stream>>>(x, idx, w0, w2_0, x1);

    // layer 1 (D = 128, x1 = [x, o0])
    sq_kernel<128><<<NP / 4, 256, 0, stream>>>(x1, sq);
    topk_kernel<128><<<NP / 32, 512, 0, stream>>>(x1, sq, idx);
    mlp_kernel<128, 1><<<NP / 2, 512, 0, stream>>>(x1, idx, w1, w2_1, out);
}

// Round 11
// 3390.346 us; speedup vs baseline: 1.6697x; 1.6697x over previous
//
#include <hip/hip_runtime.h>

#define NP   16384
#define KNN  32
#define HDIM 128
#define ODIM 64

// ---------------- squared norms ----------------
template<int D>
__global__ __launch_bounds__(256)
void sq_kernel(const float* __restrict__ X, float* __restrict__ sq) {
    const int lane = threadIdx.x & 63;
    const int row  = blockIdx.x * 4 + (threadIdx.x >> 6);
    float s = 0.f;
    #pragma unroll
    for (int d = lane; d < D; d += 64) {
        const float v = X[(size_t)row * D + d];
        s = fmaf(v, v, s);
    }
    #pragma unroll
    for (int off = 32; off; off >>= 1) s += __shfl_down(s, off);
    if (lane == 0) sq[row] = s;
}

// ---------------- top-32 neighbors (streaming, sorted register top-k) -------
// score_j = dot(x_i,x_j) - 0.5*sq_j (argmax score == argmin d2 per row).
// R8 geometry (best measured): TI=32, JC=128, 8 waves, R=4 rows/wave,
// grid=512 -> 2 blocks/CU; xi via uniform s_load (readfirstlane wave id).
// Scan: sorted top-32 (value desc, index asc on ties) in lanes 0..31;
// insert = hoisted shfl_up + ballot + popc, p==32 self-filters stale
// candidates, minv refreshed once per tile.
template<int D>
__global__ __launch_bounds__(512)
void topk_kernel(const float* __restrict__ X, const float* __restrict__ sq,
                 int* __restrict__ topIdx) {
    constexpr int TI = 32, JC = 128;
    constexpr int R  = TI / 8;               // rows per wave = 4
    constexpr int NT = NP / JC;              // 128 tiles
    constexpr int NSTG = JC * D / 4 / 512;   // float4/thread per j-tile
    __shared__ float2 xjP[(D / 2) * JC];     // [pair p][j]: (d=2p, d=2p+1) of col j

    const int t = threadIdx.x;
    const int lane = t & 63;
    const int waveU = __builtin_amdgcn_readfirstlane(t >> 6);   // SGPR wave id
    const int rowBase = blockIdx.x * TI;
    const float* __restrict__ xr = X + (size_t)(rowBase + waveU * R) * D;
    const float INF = __builtin_inff();

    // sorted top-32 per row: lane l<32 holds rank-l entry (desc value)
    float tv[R]; int tidx[R]; float minv[R];
    #pragma unroll
    for (int r = 0; r < R; ++r) { tv[r] = -INF; tidx[r] = 0x7fffffff; minv[r] = -INF; }

    float4 stg[NSTG];
    // stage tile 0
    #pragma unroll
    for (int s = 0; s < NSTG; ++s) {
        const int e = s * 512 + t;
        const int j = e & (JC - 1), dg = e >> 7;
        stg[s] = *reinterpret_cast<const float4*>(X + (size_t)j * D + 4 * dg);
    }
    #pragma unroll
    for (int s = 0; s < NSTG; ++s) {
        const int e = s * 512 + t;
        const int j = e & (JC - 1), dg = e >> 7;
        xjP[(2 * dg + 0) * JC + j] = make_float2(stg[s].x, stg[s].y);
        xjP[(2 * dg + 1) * JC + j] = make_float2(stg[s].z, stg[s].w);
    }
    __syncthreads();
    // prefetch tile 1
    #pragma unroll
    for (int s = 0; s < NSTG; ++s) {
        const int e = s * 512 + t;
        const int j = e & (JC - 1), dg = e >> 7;
        stg[s] = *reinterpret_cast<const float4*>(X + (size_t)(JC + j) * D + 4 * dg);
    }

    for (int it = 0; it < NT; ++it) {
        const int jb = it * JC;
        const float sub0 = 0.5f * sq[jb + lane];        // hidden under GEMM
        const float sub1 = 0.5f * sq[jb + 64 + lane];

        float acc0[R], acc1[R];
        #pragma unroll
        for (int r = 0; r < R; ++r) { acc0[r] = 0.f; acc1[r] = 0.f; }

        #pragma unroll 2
        for (int pg = 0; pg < D / 4; ++pg) {            // 4 d's per iter
            float4 a[R];
            #pragma unroll
            for (int r = 0; r < R; ++r)                 // uniform addr -> s_load
                a[r] = *reinterpret_cast<const float4*>(xr + (size_t)r * D + 4 * pg);
            const float2 b00 = xjP[(2 * pg + 0) * JC + lane];
            const float2 b01 = xjP[(2 * pg + 0) * JC + 64 + lane];
            const float2 b10 = xjP[(2 * pg + 1) * JC + lane];
            const float2 b11 = xjP[(2 * pg + 1) * JC + 64 + lane];
            #pragma unroll
            for (int r = 0; r < R; ++r) {               // d-ascending (numerics)
                acc0[r] = fmaf(a[r].x, b00.x, acc0[r]);
                acc0[r] = fmaf(a[r].y, b00.y, acc0[r]);
                acc0[r] = fmaf(a[r].z, b10.x, acc0[r]);
                acc0[r] = fmaf(a[r].w, b10.y, acc0[r]);
                acc1[r] = fmaf(a[r].x, b01.x, acc1[r]);
                acc1[r] = fmaf(a[r].y, b01.y, acc1[r]);
                acc1[r] = fmaf(a[r].z, b11.x, acc1[r]);
                acc1[r] = fmaf(a[r].w, b11.y, acc1[r]);
            }
        }
        __syncthreads();                   // all waves done reading xjP
        if (it + 1 < NT) {
            #pragma unroll
            for (int s = 0; s < NSTG; ++s) {
                const int e = s * 512 + t;
                const int j = e & (JC - 1), dg = e >> 7;
                xjP[(2 * dg + 0) * JC + j] = make_float2(stg[s].x, stg[s].y);
                xjP[(2 * dg + 1) * JC + j] = make_float2(stg[s].z, stg[s].w);
            }
        }
        __syncthreads();                   // next tile staged
        if (it + 2 < NT) {
            const int jb2 = (it + 2) * JC;
            #pragma unroll
            for (int s = 0; s < NSTG; ++s) {
                const int e = s * 512 + t;
                const int j = e & (JC - 1), dg = e >> 7;
                stg[s] = *reinterpret_cast<const float4*>(
                    X + (size_t)(jb2 + j) * D + 4 * dg);
            }
        }

        // scan: row-interleaved sorted inserts; stale minv + p==32 self-filter
        #pragma unroll
        for (int h = 0; h < 2; ++h) {
            float sv[R];
            unsigned long long m[R];
            #pragma unroll
            for (int r = 0; r < R; ++r) {
                sv[r] = (h ? acc1[r] : acc0[r]) - (h ? sub1 : sub0);
                m[r] = __ballot(sv[r] > minv[r]);
            }
            while (m[0] | m[1] | m[2] | m[3]) {
                #pragma unroll
                for (int r = 0; r < R; ++r) {
                    if (m[r]) {
                        const int l = __builtin_ctzll(m[r]);  // ascending j => stable
                        m[r] &= m[r] - 1;
                        const float cv = __shfl(sv[r], l);
                        const int   cj = jb + h * 64 + l;
                        const float upv = __shfl_up(tv[r], 1);   // hoisted off chain
                        const int   upi = __shfl_up(tidx[r], 1);
                        const bool ge = (lane < KNN) && (tv[r] >= cv);
                        const int p = __popcll(__ballot(ge));    // ==32 -> no-op
                        if (lane == p)                   { tv[r] = cv;  tidx[r] = cj; }
                        else if (lane > p && lane < KNN) { tv[r] = upv; tidx[r] = upi; }
                    }
                }
            }
        }
        #pragma unroll
        for (int r = 0; r < R; ++r)
            minv[r] = __shfl(tv[r], KNN - 1);   // exact refresh, once per tile
    }

    if (lane < KNN) {
        #pragma unroll
        for (int r = 0; r < R; ++r)
            topIdx[(size_t)(rowBase + waveU * R + r) * KNN + lane] = tidx[r];
    }
}

// ---------------- gather + MLP + pool + out ----------------
// h_k = A@nbr_k + B@x; pooled = mean_k clip(h_k); out = [pooled, x] @ W2^T.
// Wave -> (row, k-group); neighbor rows via uniform s_load (no LDS gather).
// Lane -> hh pair {2l, 2l+1}: A/B weights as float2 LDS reads (2-way = free).
template<int D, int LAYER>
__global__ __launch_bounds__(512)
void mlp_kernel(const float* __restrict__ X, const int* __restrict__ topIdx,
                const float* __restrict__ W, const float* __restrict__ W2,
                float* __restrict__ out) {
    constexpr int RPB = 2, WPR = 4, KPT = 8;   // 8 waves = RPB rows x WPR k-groups
    constexpr int W2C  = HDIM + D;
    constexpr int SPL2 = 512 / (RPB * ODIM);   // 4
    constexpr int CL   = W2C / SPL2;
    __shared__ float AT[D * HDIM];             // [d][hh]: B^T first, then A^T
    __shared__ float xi[RPB][D];
    __shared__ float part[RPB][WPR][HDIM];

    const int t = threadIdx.x;
    const int lane = t & 63;
    const int waveU = __builtin_amdgcn_readfirstlane(t >> 6);
    const int rowBase = blockIdx.x * RPB;
    const int row = waveU / WPR;
    const int wkb = waveU % WPR;
    const int hh2 = 2 * lane;                  // lane's hh pair

    // phase 0: stage xi and B^T
    if (t < RPB * D / 4) {
        const int i = t / (D / 4), dg = t % (D / 4);
        const float4 v = *reinterpret_cast<const float4*>(
            X + (size_t)(rowBase + i) * D + 4 * dg);
        xi[i][4 * dg + 0] = v.x; xi[i][4 * dg + 1] = v.y;
        xi[i][4 * dg + 2] = v.z; xi[i][4 * dg + 3] = v.w;
    }
    for (int e = t; e < HDIM * D / 4; e += 512) {
        const int hh = e % HDIM, dg = e / HDIM;
        const float4 v = *reinterpret_cast<const float4*>(
            W + (size_t)hh * (2 * D) + D + 4 * dg);          // B = W[:, D:2D]
        AT[(4 * dg + 0) * HDIM + hh] = v.x; AT[(4 * dg + 1) * HDIM + hh] = v.y;
        AT[(4 * dg + 2) * HDIM + hh] = v.z; AT[(4 * dg + 3) * HDIM + hh] = v.w;
    }
    __syncthreads();

    // phase 1: hself (lane's 2 hh) in registers
    float hs0 = 0.f, hs1 = 0.f;
    #pragma unroll 8
    for (int d = 0; d < D; ++d) {
        const float a = xi[row][d];            // broadcast LDS read
        const float2 b = *reinterpret_cast<const float2*>(&AT[d * HDIM + hh2]);
        hs0 = fmaf(b.x, a, hs0);
        hs1 = fmaf(b.y, a, hs1);
    }
    __syncthreads();                           // done reading AT-as-B^T

    // phase 1b: restage A^T
    for (int e = t; e < HDIM * D / 4; e += 512) {
        const int hh = e % HDIM, dg = e / HDIM;
        const float4 v = *reinterpret_cast<const float4*>(
            W + (size_t)hh * (2 * D) + 4 * dg);              // A = W[:, 0:D]
        AT[(4 * dg + 0) * HDIM + hh] = v.x; AT[(4 * dg + 1) * HDIM + hh] = v.y;
        AT[(4 * dg + 2) * HDIM + hh] = v.z; AT[(4 * dg + 3) * HDIM + hh] = v.w;
    }
    __syncthreads();

    // phase 2: GEMM; B-operand (neighbor rows) via uniform s_load
    const int* __restrict__ tIdx = topIdx + (size_t)(rowBase + row) * KNN + wkb * KPT;
    const float* nrow[KPT];
    #pragma unroll
    for (int r = 0; r < KPT; ++r)
        nrow[r] = X + (size_t)tIdx[r] * D;

    float acc0[KPT], acc1[KPT];
    #pragma unroll
    for (int r = 0; r < KPT; ++r) { acc0[r] = 0.f; acc1[r] = 0.f; }

    for (int dg = 0; dg < D / 4; ++dg) {
        float4 b[KPT];
        #pragma unroll
        for (int r = 0; r < KPT; ++r)          // uniform -> s_load_dwordx4
            b[r] = *reinterpret_cast<const float4*>(nrow[r] + 4 * dg);
        const float2 a0 = *reinterpret_cast<const float2*>(&AT[(4 * dg + 0) * HDIM + hh2]);
        const float2 a1 = *reinterpret_cast<const float2*>(&AT[(4 * dg + 1) * HDIM + hh2]);
        const float2 a2 = *reinterpret_cast<const float2*>(&AT[(4 * dg + 2) * HDIM + hh2]);
        const float2 a3 = *reinterpret_cast<const float2*>(&AT[(4 * dg + 3) * HDIM + hh2]);
        #pragma unroll
        for (int r = 0; r < KPT; ++r) {        // d-ascending accumulation
            acc0[r] = fmaf(a0.x, b[r].x, acc0[r]); acc1[r] = fmaf(a0.y, b[r].x, acc1[r]);
            acc0[r] = fmaf(a1.x, b[r].y, acc0[r]); acc1[r] = fmaf(a1.y, b[r].y, acc1[r]);
            acc0[r] = fmaf(a2.x, b[r].z, acc0[r]); acc1[r] = fmaf(a2.y, b[r].z, acc1[r]);
            acc0[r] = fmaf(a3.x, b[r].w, acc0[r]); acc1[r] = fmaf(a3.y, b[r].w, acc1[r]);
        }
    }

    // pooling partials (clip then sum over this wave's KPT neighbors)
    float p0 = 0.f, p1 = 0.f;
    #pragma unroll
    for (int r = 0; r < KPT; ++r) {
        p0 += fminf(1.f, fmaxf(-1.f, acc0[r] + hs0));
        p1 += fminf(1.f, fmaxf(-1.f, acc1[r] + hs1));
    }
    *reinterpret_cast<float2*>(&part[row][wkb][hh2]) =
        make_float2(p0 * (1.f / KNN), p1 * (1.f / KNN));
    __syncthreads();

    // phase 3: out = [pooled, x] @ W2^T, split over SPL2 column chunks
    {
        const int og   = t / SPL2;
        const int spl  = t % SPL2;
        const int orow = og >> 6, o = og & 63;
        const int c0   = spl * CL;
        float s = 0.f;
        for (int c = c0; c < c0 + CL; ++c) {
            float vsrc;
            if (c < HDIM) {
                vsrc = part[orow][0][c] + part[orow][1][c]
                     + part[orow][2][c] + part[orow][3][c];
            } else {
                vsrc = xi[orow][c - HDIM];
            }
            s = fmaf(vsrc, W2[(size_t)o * W2C + c], s);
        }
        #pragma unroll
        for (int off = SPL2 / 2; off; off >>= 1) s += __shfl_down(s, off);
        if (spl == 0) {
            if (LAYER == 0)
                out[(size_t)(rowBase + orow) * 128 + 64 + o] = s;  // x1 cols 64..127
            else
                out[(size_t)(rowBase + orow) * ODIM + o] = s;      // final output
        }
    }
    if (LAYER == 0 && t < RPB * 64) {
        const int orow = t >> 6, d = t & 63;
        out[(size_t)(rowBase + orow) * 128 + d] = xi[orow][d];     // x1 cols 0..63
    }
}

extern "C" void kernel_launch(void* const* d_in, const int* in_sizes, int n_in,
                              void* d_out, int out_size, void* d_ws, size_t ws_size,
                              hipStream_t stream) {
    const float* x    = (const float*)d_in[0];
    const float* w0   = (const float*)d_in[1];
    const float* w2_0 = (const float*)d_in[2];
    const float* w1   = (const float*)d_in[3];
    const float* w2_1 = (const float*)d_in[4];
    float* out = (float*)d_out;

    char* ws = (char*)d_ws;
    float* sq  = (float*)ws;                                     // NP floats
    int*   idx = (int*)(ws + (size_t)NP * 4);                    // NP*32 ints
    float* x1  = (float*)(ws + (size_t)NP * 4 + (size_t)NP * KNN * 4);  // NP*128

    // layer 0 (D = 64)
    sq_kernel<64><<<NP / 4, 256, 0, stream>>>(x, sq);
    topk_kernel<64><<<NP / 32, 512, 0, stream>>>(x, sq, idx);
    mlp_kernel<64, 0><<<NP / 2, 512, 0, stream>>>(x, idx, w0, w2_0, x1);

    // layer 1 (D = 128, x1 = [x, o0])
    sq_kernel<128><<<NP / 4, 256, 0, stream>>>(x1, sq);
    topk_kernel<128><<<NP / 32, 512, 0, stream>>>(x1, sq, idx);
    mlp_kernel<128, 1><<<NP / 2, 512, 0, stream>>>(x1, idx, w1, w2_1, out);
}